// Round 10
// baseline (50.054 us; speedup 1.0000x reference)
//
#include <hip/hip_runtime.h>

// 4-level lifting wavelet, fully fused. R10 = best-of-all-rounds:
//  - CHUNK=4096, BS=256, in-place LDS A[4352] = 17.4 KB -> 8 blocks/CU =
//    32 waves/CU (100% wave slots). global_load_lds staging (R5 win).
//  - Exact-state warm-up: instead of running the lifting recurrence through
//    8 halo pairs (72 FMA), compute the entry state directly: d at 6 pairs,
//    a at 4, f at 2 (36 FMA). Values identical (same FMA contraction).
//  - R9 phase structure: every z-store (threads >=128) overlaps the next
//    level's register-read (threads <128); in-place avg/det per level.
//  - avg/det arrays are pair-indexed (1 float/pair): L0 avg A[0,2176) det
//    A[2176,4352); L1 avg A[2176,3264) det A[3264,4352); L2 avg A[3264,3808)
//    det A[3808,4352); L3 avg A[3808,4080) det A[4080,4352).
#define BS    256
#define CHUNK 4096
#define HALO  256
#define NN    65536
#define LDSF  4352

template<int M, int T, int NP>
__device__ __forceinline__ void lift_read(const float* __restrict__ A, int inOff,
                                          int t, float* __restrict__ in) {
  if (t >= T) return;
  const int p0 = M * t - 8;
#pragma unroll
  for (int i = 0; i < M + 8; ++i) {
    int p = p0 + i;
    p = p < 0 ? 0 : (p >= NP ? NP - 1 : p);
    float2 v = *(const float2*)&A[inOff + 2 * p];
    in[2 * i] = v.x;
    in[2 * i + 1] = v.y;
  }
}

template<int M, int T, int NP>
__device__ __forceinline__ void lift_write(float* __restrict__ A, int avgOff,
                                           int detOff, int t,
                                           const float* __restrict__ in,
                                           const float* __restrict__ P6,
                                           const float* __restrict__ U6) {
  if (t >= T) return;
  const float P0 = P6[0], P1 = P6[1], P2 = P6[2], P3 = P6[3], P4 = P6[4], P5 = P6[5];
  const float U0 = U6[0], U1 = U6[1], U2 = U6[2], U3 = U6[3], U4 = U6[4], U5 = U6[5];
  const int p0 = M * t - 8;
  // exact-state warm-up over the 8 halo pairs (pairs p0..p0+7):
  float dd[6], aa[4], ff[2];
#pragma unroll
  for (int k = 0; k < 6; ++k)   // d at pairs p0+2..p0+7
    dd[k] = in[2 * (k + 2) + 1] - (P0 * in[2 * (k + 2)] + P1 * in[2 * (k + 1)] + P2 * in[2 * k]);
#pragma unroll
  for (int k = 0; k < 4; ++k)   // a at pairs p0+4..p0+7
    aa[k] = in[2 * (k + 4)] + (U0 * dd[k + 2] + U1 * dd[k + 1] + U2 * dd[k]);
#pragma unroll
  for (int k = 0; k < 2; ++k)   // f at pairs p0+6..p0+7
    ff[k] = dd[k + 4] - (P3 * aa[k + 2] + P4 * aa[k + 1] + P5 * aa[k]);
  float e1 = in[14], e2 = in[12];
  float d1 = dd[5], d2 = dd[4], a1 = aa[3], a2 = aa[2], f1 = ff[1], f2 = ff[0];
#pragma unroll
  for (int i = 8; i < M + 8; ++i) {
    float e0 = in[2 * i], o0 = in[2 * i + 1];
    float d0 = o0 - (P0 * e0 + P1 * e1 + P2 * e2);
    float a0 = e0 + (U0 * d0 + U1 * d1 + U2 * d2);
    float f0 = d0 - (P3 * a0 + P4 * a1 + P5 * a2);
    float b0 = a0 + (U3 * f0 + U4 * f1 + U5 * f2);
    int p = p0 + i;               // = M*t + (i-8) >= 0
    if (p < NP) { A[avgOff + p] = b0; A[detOff + p] = f0; }
    e2 = e1; e1 = e0; d2 = d1; d1 = d0; a2 = a1; a1 = a0; f2 = f1; f1 = f0;
  }
}

__global__ __launch_bounds__(BS, 8)
void wavelet_fused_kernel(const float* __restrict__ x,
                          const float* __restrict__ Pc,
                          const float* __restrict__ Uc,
                          float* __restrict__ out) {
  __shared__ __align__(16) float A[LDSF];   // 17.4 KB

  const int tid  = threadIdx.x;
  const int wave = tid >> 6;
  const int lane = tid & 63;
  const int cx   = blockIdx.x;    // chunk 0..15
  const int row  = blockIdx.y;    // row 0..511
  const int S    = cx * CHUNK;

  // ---- stage CHUNK + HALO = 4352 floats (1088 float4 = 17 wave-slices) ----
  {
    const float4* x4 = (const float4*)(x + (size_t)row * NN);
    const int base4 = ((S - HALO) & (NN - 1)) >> 2;
    for (int s = wave; s < 17; s += 4) {
      const float4* g = &x4[(base4 + s * 64 + lane) & (NN / 4 - 1)];
      __builtin_amdgcn_global_load_lds(
          (const __attribute__((address_space(1))) void*)g,
          (__attribute__((address_space(3))) void*)&A[s * 256], 16, 0, 0);
    }
  }
  __syncthreads();   // (1)

  float4* z0 = (float4*)out + (size_t)row * 8192 + (S >> 3);
  float4* z1 = (float4*)out + 4194304 + row * 4096 + (S >> 4);
  float4* z2 = (float4*)out + 6291456 + row * 2048 + (S >> 5);
  float4* z3 = (float4*)out + 7340032 + row * 1024 + (S >> 6);
  float4* z4 = (float4*)out + 7864320 + row * 1024 + (S >> 6);

  // ---- L0: 2176 pairs in [0,4352) -> avg [0,2176), det [2176,4352) ----
  {
    float in0[34];
    lift_read<9, 242, 2176>(A, 0, tid, in0);
    __syncthreads();   // (2) WAR
    lift_write<9, 242, 2176>(A, 0, 2176, tid, in0, Pc, Uc);
  }
  __syncthreads();     // (3)

  // ---- z0 store (tid>=128; avg pairs 128..2176 = A[128..2176)) ----
  // ---- || L1 read (tid<128; det0 at A[2176+2r]) ----
  float in1[34];
  if (tid >= 128) {
    const float4* s = (const float4*)(A + 128);
    const int t = tid - 128;
#pragma unroll
    for (int k = 0; k < 4; ++k) z0[t + 128 * k] = s[t + 128 * k];
  } else {
    lift_read<9, 121, 1088>(A, 2176, tid, in1);
  }
  __syncthreads();     // (4) z0 reads done + L1 WAR
  lift_write<9, 121, 1088>(A, 2176, 3264, tid, in1, Pc + 6, Uc + 6);
  __syncthreads();     // (5)

  // ---- z1 store (avg1 pairs 64..1088 = A[2240..3264)) || L2 read ----
  float in2[34];
  if (tid >= 128) {
    const float4* s = (const float4*)(A + 2240);
    const int t = tid - 128;
#pragma unroll
    for (int k = 0; k < 2; ++k) z1[t + 128 * k] = s[t + 128 * k];
  } else {
    lift_read<9, 61, 544>(A, 3264, tid, in2);
  }
  __syncthreads();     // (6)
  lift_write<9, 61, 544>(A, 3264, 3808, tid, in2, Pc + 12, Uc + 12);
  __syncthreads();     // (7)

  // ---- z2 store (avg2 pairs 32..544 = A[3296..3808)) || L3 read ----
  float in3[26];
  if (tid >= 128) {
    z2[tid - 128] = ((const float4*)(A + 3296))[tid - 128];
  } else {
    lift_read<5, 55, 272>(A, 3808, tid, in3);
  }
  __syncthreads();     // (8)
  lift_write<5, 55, 272>(A, 3808, 4080, tid, in3, Pc + 18, Uc + 18);
  __syncthreads();     // (9)

  // ---- z3 (avg3 pairs 16..272 = A[3824..4080)), z4 (det3 = A[4096..4352)) ----
  if (tid < 64)        z3[tid] = ((const float4*)(A + 3824))[tid];
  else if (tid < 128)  z4[tid - 64] = ((const float4*)(A + 4096))[tid - 64];
}

extern "C" void kernel_launch(void* const* d_in, const int* in_sizes, int n_in,
                              void* d_out, int out_size, void* d_ws, size_t ws_size,
                              hipStream_t stream) {
  const float* x  = (const float*)d_in[0];
  const float* Pc = (const float*)d_in[1];
  const float* Uc = (const float*)d_in[2];
  float* out = (float*)d_out;

  dim3 grid(NN / CHUNK, 512, 1);   // 16 x 512 = 8192 blocks
  dim3 block(BS, 1, 1);
  wavelet_fused_kernel<<<grid, block, 0, stream>>>(x, Pc, Uc, out);
}

// Round 12
// 48.182 us; speedup vs baseline: 1.0389x; 1.0389x over previous
//
#include <hip/hip_runtime.h>

// 4-level lifting wavelet, fully fused. R12 = R10 + NON-TEMPORAL output
// stores (R11 fixed: __builtin_nontemporal_store needs a clang vector type,
// not HIP's float4 struct). z* are written once and never re-read; nt stores
// keep `out` from thrashing L2/L3, so x (134 MB < 256 MB L3) stays
// L3-resident across replays and reads stop hitting HBM.
#define BS    256
#define CHUNK 4096
#define HALO  256
#define NN    65536
#define LDSF  4352

typedef float f4 __attribute__((ext_vector_type(4)));

__device__ __forceinline__ void ntst4(float* dst, const float* src) {
  __builtin_nontemporal_store(*(const f4*)src, (f4*)dst);
}

template<int M, int T, int NP>
__device__ __forceinline__ void lift_read(const float* __restrict__ A, int inOff,
                                          int t, float* __restrict__ in) {
  if (t >= T) return;
  const int p0 = M * t - 8;
#pragma unroll
  for (int i = 0; i < M + 8; ++i) {
    int p = p0 + i;
    p = p < 0 ? 0 : (p >= NP ? NP - 1 : p);
    float2 v = *(const float2*)&A[inOff + 2 * p];
    in[2 * i] = v.x;
    in[2 * i + 1] = v.y;
  }
}

template<int M, int T, int NP>
__device__ __forceinline__ void lift_write(float* __restrict__ A, int avgOff,
                                           int detOff, int t,
                                           const float* __restrict__ in,
                                           const float* __restrict__ P6,
                                           const float* __restrict__ U6) {
  if (t >= T) return;
  const float P0 = P6[0], P1 = P6[1], P2 = P6[2], P3 = P6[3], P4 = P6[4], P5 = P6[5];
  const float U0 = U6[0], U1 = U6[1], U2 = U6[2], U3 = U6[3], U4 = U6[4], U5 = U6[5];
  const int p0 = M * t - 8;
  float dd[6], aa[4], ff[2];
#pragma unroll
  for (int k = 0; k < 6; ++k)
    dd[k] = in[2 * (k + 2) + 1] - (P0 * in[2 * (k + 2)] + P1 * in[2 * (k + 1)] + P2 * in[2 * k]);
#pragma unroll
  for (int k = 0; k < 4; ++k)
    aa[k] = in[2 * (k + 4)] + (U0 * dd[k + 2] + U1 * dd[k + 1] + U2 * dd[k]);
#pragma unroll
  for (int k = 0; k < 2; ++k)
    ff[k] = dd[k + 4] - (P3 * aa[k + 2] + P4 * aa[k + 1] + P5 * aa[k]);
  float e1 = in[14], e2 = in[12];
  float d1 = dd[5], d2 = dd[4], a1 = aa[3], a2 = aa[2], f1 = ff[1], f2 = ff[0];
#pragma unroll
  for (int i = 8; i < M + 8; ++i) {
    float e0 = in[2 * i], o0 = in[2 * i + 1];
    float d0 = o0 - (P0 * e0 + P1 * e1 + P2 * e2);
    float a0 = e0 + (U0 * d0 + U1 * d1 + U2 * d2);
    float f0 = d0 - (P3 * a0 + P4 * a1 + P5 * a2);
    float b0 = a0 + (U3 * f0 + U4 * f1 + U5 * f2);
    int p = p0 + i;
    if (p < NP) { A[avgOff + p] = b0; A[detOff + p] = f0; }
    e2 = e1; e1 = e0; d2 = d1; d1 = d0; a2 = a1; a1 = a0; f2 = f1; f1 = f0;
  }
}

__global__ __launch_bounds__(BS, 8)
void wavelet_fused_kernel(const float* __restrict__ x,
                          const float* __restrict__ Pc,
                          const float* __restrict__ Uc,
                          float* __restrict__ out) {
  __shared__ __align__(16) float A[LDSF];   // 17.4 KB

  const int tid  = threadIdx.x;
  const int wave = tid >> 6;
  const int lane = tid & 63;
  const int cx   = blockIdx.x;    // chunk 0..15
  const int row  = blockIdx.y;    // row 0..511
  const int S    = cx * CHUNK;

  // ---- stage CHUNK + HALO = 4352 floats (1088 float4 = 17 wave-slices) ----
  {
    const float4* x4 = (const float4*)(x + (size_t)row * NN);
    const int base4 = ((S - HALO) & (NN - 1)) >> 2;
    for (int s = wave; s < 17; s += 4) {
      const float4* g = &x4[(base4 + s * 64 + lane) & (NN / 4 - 1)];
      __builtin_amdgcn_global_load_lds(
          (const __attribute__((address_space(1))) void*)g,
          (__attribute__((address_space(3))) void*)&A[s * 256], 16, 0, 0);
    }
  }
  __syncthreads();   // (1)

  float* z0 = out + (size_t)row * 32768 + (S >> 1);
  float* z1 = out + 16777216 + (size_t)row * 16384 + (S >> 2);
  float* z2 = out + 25165824 + (size_t)row * 8192 + (S >> 3);
  float* z3 = out + 29360128 + (size_t)row * 4096 + (S >> 4);
  float* z4 = out + 31457280 + (size_t)row * 4096 + (S >> 4);

  // ---- L0: 2176 pairs in [0,4352) -> avg [0,2176), det [2176,4352) ----
  {
    float in0[34];
    lift_read<9, 242, 2176>(A, 0, tid, in0);
    __syncthreads();   // (2) WAR
    lift_write<9, 242, 2176>(A, 0, 2176, tid, in0, Pc, Uc);
  }
  __syncthreads();     // (3)

  // ---- z0 store (tid>=128; avg pairs 128..2176 = A[128..2176)) ----
  // ---- || L1 read (tid<128) ----
  float in1[34];
  if (tid >= 128) {
    const int t = tid - 128;
#pragma unroll
    for (int k = 0; k < 4; ++k)
      ntst4(z0 + 4 * (t + 128 * k), A + 128 + 4 * (t + 128 * k));
  } else {
    lift_read<9, 121, 1088>(A, 2176, tid, in1);
  }
  __syncthreads();     // (4)
  lift_write<9, 121, 1088>(A, 2176, 3264, tid, in1, Pc + 6, Uc + 6);
  __syncthreads();     // (5)

  // ---- z1 store (avg1 pairs 64..1088 = A[2240..3264)) || L2 read ----
  float in2[34];
  if (tid >= 128) {
    const int t = tid - 128;
#pragma unroll
    for (int k = 0; k < 2; ++k)
      ntst4(z1 + 4 * (t + 128 * k), A + 2240 + 4 * (t + 128 * k));
  } else {
    lift_read<9, 61, 544>(A, 3264, tid, in2);
  }
  __syncthreads();     // (6)
  lift_write<9, 61, 544>(A, 3264, 3808, tid, in2, Pc + 12, Uc + 12);
  __syncthreads();     // (7)

  // ---- z2 store (avg2 pairs 32..544 = A[3296..3808)) || L3 read ----
  float in3[26];
  if (tid >= 128) {
    const int t = tid - 128;
    ntst4(z2 + 4 * t, A + 3296 + 4 * t);
  } else {
    lift_read<5, 55, 272>(A, 3808, tid, in3);
  }
  __syncthreads();     // (8)
  lift_write<5, 55, 272>(A, 3808, 4080, tid, in3, Pc + 18, Uc + 18);
  __syncthreads();     // (9)

  // ---- z3 (avg3 pairs 16..272 = A[3824..4080)), z4 (det3 = A[4096..4352)) ----
  if (tid < 64)        ntst4(z3 + 4 * tid, A + 3824 + 4 * tid);
  else if (tid < 128)  ntst4(z4 + 4 * (tid - 64), A + 4096 + 4 * (tid - 64));
}

extern "C" void kernel_launch(void* const* d_in, const int* in_sizes, int n_in,
                              void* d_out, int out_size, void* d_ws, size_t ws_size,
                              hipStream_t stream) {
  const float* x  = (const float*)d_in[0];
  const float* Pc = (const float*)d_in[1];
  const float* Uc = (const float*)d_in[2];
  float* out = (float*)d_out;

  dim3 grid(NN / CHUNK, 512, 1);   // 16 x 512 = 8192 blocks
  dim3 block(BS, 1, 1);
  wavelet_fused_kernel<<<grid, block, 0, stream>>>(x, Pc, Uc, out);
}